// Round 4
// baseline (226.618 us; speedup 1.0000x reference)
//
#include <hip/hip_runtime.h>
#include <stdint.h>

#define NH    16
#define HD    64
#define HDIM  1024
#define BATCH 4
#define SEQ   2048

typedef __attribute__((ext_vector_type(4))) float f32x4;
typedef __attribute__((ext_vector_type(8))) __bf16 bf16x8;
typedef __attribute__((ext_vector_type(8))) unsigned short u16x8;

#define LOG2E 1.44269504088896340736f

__device__ __forceinline__ unsigned short f2bf(float f) {
  unsigned int u = __builtin_bit_cast(unsigned int, f);
  u += 0x7fffu + ((u >> 16) & 1u);   // RNE
  return (unsigned short)(u >> 16);
}

__device__ __forceinline__ f32x4 mfma16(u16x8 a, u16x8 b, f32x4 c) {
  return __builtin_amdgcn_mfma_f32_16x16x32_bf16(
      __builtin_bit_cast(bf16x8, a), __builtin_bit_cast(bf16x8, b), c, 0, 0, 0);
}

#define GLOAD_LDS16(g, l)                                                      \
  __builtin_amdgcn_global_load_lds(                                            \
      (const __attribute__((address_space(1))) unsigned int*)(g),              \
      (__attribute__((address_space(3))) unsigned int*)(l), 16, 0, 0)

// ---------- fp32 -> bf16 bits, x8 vectorized ----------
__global__ __launch_bounds__(256) void cvt_x_kernel(
    const float* __restrict__ src, unsigned short* __restrict__ dst) {
  int i = (blockIdx.x * 256 + threadIdx.x) * 8;
  f32x4 a = *reinterpret_cast<const f32x4*>(src + i);
  f32x4 b = *reinterpret_cast<const f32x4*>(src + i + 4);
  u16x8 o;
  o[0] = f2bf(a[0]); o[1] = f2bf(a[1]); o[2] = f2bf(a[2]); o[3] = f2bf(a[3]);
  o[4] = f2bf(b[0]); o[5] = f2bf(b[1]); o[6] = f2bf(b[2]); o[7] = f2bf(b[3]);
  *reinterpret_cast<u16x8*>(dst + i) = o;
}

// ---------- W[k][n] fp32 -> Wcat[z][n][k] bf16, LDS-tiled transpose ----------
// grid (16,16,3); both global sides coalesced; 64x65 f32 LDS tile.
__global__ __launch_bounds__(256) void cvt_wt_kernel(
    const float* __restrict__ Wq, const float* __restrict__ Wk,
    const float* __restrict__ Wv, unsigned short* __restrict__ Wcat) {
  const float* __restrict__ src =
      (blockIdx.z == 0) ? Wq : (blockIdx.z == 1) ? Wk : Wv;
  unsigned short* __restrict__ dst = Wcat + (size_t)blockIdx.z * HDIM * HDIM;
  __shared__ float T[64][65];
  const int k0 = blockIdx.y * 64, n0 = blockIdx.x * 64;
  const int tid = threadIdx.x;
  const int lrow = tid >> 4, c4 = (tid & 15) * 4;
  for (int it = 0; it < 4; ++it) {
    f32x4 v = *reinterpret_cast<const f32x4*>(
        &src[(k0 + it * 16 + lrow) * HDIM + n0 + c4]);
    T[it * 16 + lrow][c4 + 0] = v[0];
    T[it * 16 + lrow][c4 + 1] = v[1];
    T[it * 16 + lrow][c4 + 2] = v[2];
    T[it * 16 + lrow][c4 + 3] = v[3];
  }
  __syncthreads();
  const int n = tid >> 2, kc = (tid & 3) * 16;
  u16x8 o0, o1;
  for (int j = 0; j < 8; ++j) o0[j] = f2bf(T[kc + j][n]);
  for (int j = 0; j < 8; ++j) o1[j] = f2bf(T[kc + 8 + j][n]);
  *reinterpret_cast<u16x8*>(&dst[(n0 + n) * HDIM + k0 + kc]) = o0;
  *reinterpret_cast<u16x8*>(&dst[(n0 + n) * HDIM + k0 + kc + 8]) = o1;
}

// ---------- fused QKV projection: [8192x1024] @ [1024x3072] ----------
// 2-phase double-buffered (T3-minimum), BK=64, 128x128 tile, one barrier per
// K-step: STAGE(next) issued BEFORE compute(cur); barrier's implicit
// vmcnt(0)+lgkmcnt(0) drain makes next buffer ready. Wcat = [z][n][k] bf16.
// Epilogue routes per z: Q scaled by log2e/8 -> Qs[b,h,s,d]; K -> Kb[b,h,s,d];
// V -> Vt[b,h,d,s] (transposed for PV fragment loads).
__global__ __launch_bounds__(256) void proj_kernel(
    const unsigned short* __restrict__ Xb,
    const unsigned short* __restrict__ Wcat,
    const float* __restrict__ bq, const float* __restrict__ bk,
    const float* __restrict__ bv,
    unsigned short* __restrict__ Qs, unsigned short* __restrict__ Kb,
    unsigned short* __restrict__ Vt) {
  const int m0 = blockIdx.x * 128;
  const int n0g = blockIdx.y * 128;        // 0..3071, z-uniform per block
  __shared__ unsigned short As[2][128 * 64];
  __shared__ unsigned short Bs[2][128 * 64];
  const int tid = threadIdx.x, lane = tid & 63, w = tid >> 6;
  const int wm = (w >> 1) * 64, wn = (w & 1) * 64;
  const int cl = lane & 15, rg = lane >> 4;
  f32x4 acc[4][4] = {};

#define PSTAGE(buf, k0)                                                        \
  do {                                                                         \
    for (int p = 0; p < 4; ++p) {                                              \
      int c = p * 256 + tid, row = c >> 3, ch = c & 7;                         \
      GLOAD_LDS16(Xb + (m0 + row) * HDIM + (k0) + ch * 8, &As[buf][c * 8]);    \
      GLOAD_LDS16(Wcat + (size_t)(n0g + row) * HDIM + (k0) + ch * 8,           \
                  &Bs[buf][c * 8]);                                            \
    }                                                                          \
  } while (0)

  PSTAGE(0, 0);
  __syncthreads();
  for (int kt = 0; kt < HDIM / 64; ++kt) {
    const int cur = kt & 1;
    if (kt + 1 < HDIM / 64) PSTAGE(cur ^ 1, (kt + 1) * 64);
    for (int ks = 0; ks < 2; ++ks) {
      u16x8 af[4], bfr[4];
      for (int m = 0; m < 4; ++m)
        af[m] = *reinterpret_cast<const u16x8*>(
            &As[cur][(wm + m * 16 + cl) * 64 + ks * 32 + rg * 8]);
      for (int n = 0; n < 4; ++n)
        bfr[n] = *reinterpret_cast<const u16x8*>(
            &Bs[cur][(wn + n * 16 + cl) * 64 + ks * 32 + rg * 8]);
      for (int m = 0; m < 4; ++m)
        for (int n = 0; n < 4; ++n)
          acc[m][n] = mfma16(af[m], bfr[n], acc[m][n]);
    }
    __syncthreads();
  }
#undef PSTAGE

  const int z = n0g >> 10;
  const float* __restrict__ bias = (z == 0) ? bq : (z == 1) ? bk : bv;
  const int nbase = n0g & 1023;
  for (int n = 0; n < 4; ++n) {
    const int col = nbase + wn + n * 16 + cl;
    const float bval = bias[col];
    const int h = col >> 6, d = col & 63;
    for (int m = 0; m < 4; ++m) {
      const int rbase = m0 + wm + m * 16 + rg * 4;
      for (int r = 0; r < 4; ++r) {
        const int row = rbase + r;
        const int b = row >> 11, s = row & 2047;
        float v = acc[m][n][r] + bval;
        if (z == 0) {
          Qs[((b * NH + h) * SEQ + s) * HD + d] = f2bf(v * (0.125f * LOG2E));
        } else if (z == 1) {
          Kb[((b * NH + h) * SEQ + s) * HD + d] = f2bf(v);
        } else {
          Vt[((b * NH + h) * HD + d) * SEQ + s] = f2bf(v);
        }
      }
    }
  }
}

// ---------- flash attention, LDS-staged K/V double-buffer, KVBLK=64 ----------
// (unchanged from round 3 — 2-phase pipeline, XOR-swizzled K/V, no-max
// softmax in exp2 domain, XCD-aware remap for L2-resident K/V)
__global__ __launch_bounds__(256, 3) void attn_kernel(
    const unsigned short* __restrict__ Qs, const unsigned short* __restrict__ Kb,
    const unsigned short* __restrict__ Vt, const float* __restrict__ mask,
    float* __restrict__ out) {
  const int bid = blockIdx.x;
  const int lbid = (bid & 7) * 128 + (bid >> 3);
  const int head = lbid >> 4;
  const int qchunk = lbid & 15;
  const int b = head >> 4, h = head & 15;
  const int tid = threadIdx.x, lane = tid & 63, w = tid >> 6;
  const int q0 = qchunk * 128 + w * 32;
  const int cl = lane & 15, rg = lane >> 4;

  __shared__ unsigned short Kbuf[2][64 * 64];
  __shared__ unsigned short Vbuf[2][64 * 64];
  __shared__ __bf16 P[4][2][32][40];

  const int srow0 = tid >> 3, scl0 = tid & 7;
  const int srow1 = (256 + tid) >> 3, scl1 = tid & 7;
  const unsigned short* kg0 = Kb + (head * SEQ + srow0) * HD + ((scl0 ^ (srow0 & 7)) * 8);
  const unsigned short* kg1 = Kb + (head * SEQ + srow1) * HD + ((scl1 ^ (srow1 & 7)) * 8);
  const unsigned short* vg0 = Vt + (head * HD + srow0) * SEQ + ((scl0 ^ (srow0 & 7)) * 8);
  const unsigned short* vg1 = Vt + (head * HD + srow1) * SEQ + ((scl1 ^ (srow1 & 7)) * 8);

#define STAGE(buf, kk)                                                         \
  do {                                                                         \
    GLOAD_LDS16(kg0 + (size_t)(kk)*HD, &Kbuf[buf][tid * 8]);                   \
    GLOAD_LDS16(kg1 + (size_t)(kk)*HD, &Kbuf[buf][(256 + tid) * 8]);           \
    GLOAD_LDS16(vg0 + (kk), &Vbuf[buf][tid * 8]);                              \
    GLOAD_LDS16(vg1 + (kk), &Vbuf[buf][(256 + tid) * 8]);                      \
  } while (0)

  u16x8 qf[2][2];
  for (int rf = 0; rf < 2; ++rf)
    for (int dc = 0; dc < 2; ++dc)
      qf[rf][dc] = *reinterpret_cast<const u16x8*>(
          Qs + (head * SEQ + q0 + rf * 16 + cl) * HD + dc * 32 + rg * 8);

  f32x4 ctx[2][4] = {};
  float lrow[2][4] = {};

  STAGE(0, 0);
  __syncthreads();

  for (int t = 0; t < SEQ / 64; ++t) {
    const int cur = t & 1;
    const int kk = t * 64;
    if (t + 1 < SEQ / 64) STAGE(cur ^ 1, kk + 64);

    float mv[4];
    for (int cf = 0; cf < 4; ++cf)
      mv[cf] = mask[b * SEQ + kk + cf * 16 + cl] * LOG2E;

    f32x4 s[2][4] = {};
    for (int cf = 0; cf < 4; ++cf) {
      const int krow = cf * 16 + cl;
      u16x8 kf0 = *reinterpret_cast<const u16x8*>(
          &Kbuf[cur][krow * 64 + ((rg ^ (krow & 7)) * 8)]);
      u16x8 kf1 = *reinterpret_cast<const u16x8*>(
          &Kbuf[cur][krow * 64 + (((4 | rg) ^ (krow & 7)) * 8)]);
      for (int rf = 0; rf < 2; ++rf) {
        s[rf][cf] = mfma16(qf[rf][0], kf0, s[rf][cf]);
        s[rf][cf] = mfma16(qf[rf][1], kf1, s[rf][cf]);
      }
    }

    for (int jj = 0; jj < 2; ++jj) {
      for (int rf = 0; rf < 2; ++rf)
        for (int cc = 0; cc < 2; ++cc) {
          const int cf = jj * 2 + cc;
          for (int r = 0; r < 4; ++r) {
            float p = __builtin_amdgcn_exp2f(s[rf][cf][r] + mv[cf]);
            lrow[rf][r] += p;
            P[w][jj][rf * 16 + rg * 4 + r][cc * 16 + cl] = (__bf16)p;
          }
        }
      u16x8 pa[2];
      for (int rf = 0; rf < 2; ++rf)
        pa[rf] = *reinterpret_cast<const u16x8*>(&P[w][jj][rf * 16 + cl][rg * 8]);
      for (int df = 0; df < 4; ++df) {
        const int vrow = df * 16 + cl;
        u16x8 vf = *reinterpret_cast<const u16x8*>(
            &Vbuf[cur][vrow * 64 + ((((jj << 2) | rg) ^ (vrow & 7)) * 8)]);
        for (int rf = 0; rf < 2; ++rf)
          ctx[rf][df] = mfma16(pa[rf], vf, ctx[rf][df]);
      }
    }
    __syncthreads();
  }

  for (int rf = 0; rf < 2; ++rf)
    for (int off = 1; off < 16; off <<= 1)
      for (int r = 0; r < 4; ++r)
        lrow[rf][r] += __shfl_xor(lrow[rf][r], off);

  for (int rf = 0; rf < 2; ++rf) {
    float inv[4];
    for (int r = 0; r < 4; ++r) inv[r] = 1.0f / lrow[rf][r];
    for (int df = 0; df < 4; ++df)
      for (int r = 0; r < 4; ++r)
        out[(b * SEQ + q0 + rf * 16 + rg * 4 + r) * HDIM + h * HD + df * 16 + cl] =
            ctx[rf][df][r] * inv[r];
  }
#undef STAGE
}

extern "C" void kernel_launch(void* const* d_in, const int* in_sizes, int n_in,
                              void* d_out, int out_size, void* d_ws, size_t ws_size,
                              hipStream_t stream) {
  const float* hs   = (const float*)d_in[0];
  const float* mask = (const float*)d_in[1];
  // d_in[2] intent_ids, d_in[9..11] intent path: unused (softmax shift-invariant)
  const float* Wq = (const float*)d_in[3];
  const float* bq = (const float*)d_in[4];
  const float* Wk = (const float*)d_in[5];
  const float* bk = (const float*)d_in[6];
  const float* Wv = (const float*)d_in[7];
  const float* bv = (const float*)d_in[8];
  float* out = (float*)d_out;

  uint8_t* ws = (uint8_t*)d_ws;
  const size_t MB = 1024 * 1024;
  unsigned short* Xb   = (unsigned short*)(ws);            // 16 MB
  unsigned short* Wcat = (unsigned short*)(ws + 16 * MB);  // 6 MB: [3][1024][1024]
  unsigned short* Qsp  = (unsigned short*)(ws + 22 * MB);  // 16 MB: [64][2048][64]
  unsigned short* Kbp  = (unsigned short*)(ws + 38 * MB);  // 16 MB
  unsigned short* Vtp  = (unsigned short*)(ws + 54 * MB);  // 16 MB: [64][64][2048]

  cvt_x_kernel<<<4096, 256, 0, stream>>>(hs, Xb);
  cvt_wt_kernel<<<dim3(16, 16, 3), 256, 0, stream>>>(Wq, Wk, Wv, Wcat);
  proj_kernel<<<dim3(64, 24), 256, 0, stream>>>(Xb, Wcat, bq, bk, bv,
                                                Qsp, Kbp, Vtp);
  attn_kernel<<<1024, 256, 0, stream>>>(Qsp, Kbp, Vtp, mask, out);
}

// Round 5
// 191.925 us; speedup vs baseline: 1.1808x; 1.1808x over previous
//
#include <hip/hip_runtime.h>
#include <stdint.h>

#define NH    16
#define HD    64
#define HDIM  1024
#define BATCH 4
#define SEQ   2048

typedef __attribute__((ext_vector_type(4))) float f32x4;
typedef __attribute__((ext_vector_type(8))) __bf16 bf16x8;
typedef __attribute__((ext_vector_type(8))) unsigned short u16x8;
typedef __attribute__((ext_vector_type(4))) unsigned short u16x4;

#define LOG2E 1.44269504088896340736f

__device__ __forceinline__ unsigned short f2bf(float f) {
  unsigned int u = __builtin_bit_cast(unsigned int, f);
  u += 0x7fffu + ((u >> 16) & 1u);   // RNE
  return (unsigned short)(u >> 16);
}

__device__ __forceinline__ f32x4 mfma16(u16x8 a, u16x8 b, f32x4 c) {
  return __builtin_amdgcn_mfma_f32_16x16x32_bf16(
      __builtin_bit_cast(bf16x8, a), __builtin_bit_cast(bf16x8, b), c, 0, 0, 0);
}

#define GLOAD_LDS16(g, l)                                                      \
  __builtin_amdgcn_global_load_lds(                                            \
      (const __attribute__((address_space(1))) unsigned int*)(g),              \
      (__attribute__((address_space(3))) unsigned int*)(l), 16, 0, 0)

// ---------- fp32 -> bf16 bits, x8 vectorized ----------
__global__ __launch_bounds__(256) void cvt_x_kernel(
    const float* __restrict__ src, unsigned short* __restrict__ dst) {
  int i = (blockIdx.x * 256 + threadIdx.x) * 8;
  f32x4 a = *reinterpret_cast<const f32x4*>(src + i);
  f32x4 b = *reinterpret_cast<const f32x4*>(src + i + 4);
  u16x8 o;
  o[0] = f2bf(a[0]); o[1] = f2bf(a[1]); o[2] = f2bf(a[2]); o[3] = f2bf(a[3]);
  o[4] = f2bf(b[0]); o[5] = f2bf(b[1]); o[6] = f2bf(b[2]); o[7] = f2bf(b[3]);
  *reinterpret_cast<u16x8*>(dst + i) = o;
}

// ---------- W[k][n] fp32 -> Wcat[z][n][k] bf16, LDS-tiled transpose ----------
__global__ __launch_bounds__(256) void cvt_wt_kernel(
    const float* __restrict__ Wq, const float* __restrict__ Wk,
    const float* __restrict__ Wv, unsigned short* __restrict__ Wcat) {
  const float* __restrict__ src =
      (blockIdx.z == 0) ? Wq : (blockIdx.z == 1) ? Wk : Wv;
  unsigned short* __restrict__ dst = Wcat + (size_t)blockIdx.z * HDIM * HDIM;
  __shared__ float T[64][65];
  const int k0 = blockIdx.y * 64, n0 = blockIdx.x * 64;
  const int tid = threadIdx.x;
  const int lrow = tid >> 4, c4 = (tid & 15) * 4;
  for (int it = 0; it < 4; ++it) {
    f32x4 v = *reinterpret_cast<const f32x4*>(
        &src[(k0 + it * 16 + lrow) * HDIM + n0 + c4]);
    T[it * 16 + lrow][c4 + 0] = v[0];
    T[it * 16 + lrow][c4 + 1] = v[1];
    T[it * 16 + lrow][c4 + 2] = v[2];
    T[it * 16 + lrow][c4 + 3] = v[3];
  }
  __syncthreads();
  const int n = tid >> 2, kc = (tid & 3) * 16;
  u16x8 o0, o1;
  for (int j = 0; j < 8; ++j) o0[j] = f2bf(T[kc + j][n]);
  for (int j = 0; j < 8; ++j) o1[j] = f2bf(T[kc + 8 + j][n]);
  *reinterpret_cast<u16x8*>(&dst[(n0 + n) * HDIM + k0 + kc]) = o0;
  *reinterpret_cast<u16x8*>(&dst[(n0 + n) * HDIM + k0 + kc + 8]) = o1;
}

// ---------- fused QKV projection: [8192x1024] @ [1024x3072] ----------
// 2-phase double-buffered, BK=64, 128x128 tile, ONE barrier per K-step.
// T2 XOR-swizzle (rule #21, both-sides): LDS dest stays linear for
// global_load_lds; the GLOBAL source chunk is pre-swizzled ch^=(row&7), and
// the ds_read chunk applies the same XOR -> LDS[row][c] == global[row][c].
// Kills the BK=64 16-way bank conflict (row stride 128B == bank period).
__global__ __launch_bounds__(256) void proj_kernel(
    const unsigned short* __restrict__ Xb,
    const unsigned short* __restrict__ Wcat,
    const float* __restrict__ bq, const float* __restrict__ bk,
    const float* __restrict__ bv,
    unsigned short* __restrict__ Qs, unsigned short* __restrict__ Kb,
    unsigned short* __restrict__ Vt) {
  const int m0 = blockIdx.x * 128;
  const int n0g = blockIdx.y * 128;        // 0..3071, z-uniform per block
  __shared__ unsigned short As[2][128 * 64];
  __shared__ unsigned short Bs[2][128 * 64];
  const int tid = threadIdx.x, lane = tid & 63, w = tid >> 6;
  const int wm = (w >> 1) * 64, wn = (w & 1) * 64;
  const int cl = lane & 15, rg = lane >> 4;
  f32x4 acc[4][4] = {};

  // staging: thread covers 4 chunks c = p*256+tid; row=c>>3, ch=c&7;
  // source chunk swizzled by row&7, LDS dest linear.
#define PSTAGE(buf, k0)                                                        \
  do {                                                                         \
    for (int p = 0; p < 4; ++p) {                                              \
      int c = p * 256 + tid, row = c >> 3, ch = c & 7;                         \
      int sch = (ch ^ (row & 7)) * 8;                                          \
      GLOAD_LDS16(Xb + (m0 + row) * HDIM + (k0) + sch, &As[buf][c * 8]);       \
      GLOAD_LDS16(Wcat + (size_t)(n0g + row) * HDIM + (k0) + sch,              \
                  &Bs[buf][c * 8]);                                            \
    }                                                                          \
  } while (0)

  PSTAGE(0, 0);
  __syncthreads();
  for (int kt = 0; kt < HDIM / 64; ++kt) {
    const int cur = kt & 1;
    if (kt + 1 < HDIM / 64) PSTAGE(cur ^ 1, (kt + 1) * 64);
    for (int ks = 0; ks < 2; ++ks) {
      u16x8 af[4], bfr[4];
      for (int m = 0; m < 4; ++m) {
        const int row = wm + m * 16 + cl;
        af[m] = *reinterpret_cast<const u16x8*>(
            &As[cur][row * 64 + (((ks * 4 + rg) ^ (row & 7)) * 8)]);
      }
      for (int n = 0; n < 4; ++n) {
        const int row = wn + n * 16 + cl;
        bfr[n] = *reinterpret_cast<const u16x8*>(
            &Bs[cur][row * 64 + (((ks * 4 + rg) ^ (row & 7)) * 8)]);
      }
      for (int m = 0; m < 4; ++m)
        for (int n = 0; n < 4; ++n)
          acc[m][n] = mfma16(af[m], bfr[n], acc[m][n]);
    }
    __syncthreads();
  }
#undef PSTAGE

  const int z = n0g >> 10;
  const float* __restrict__ bias = (z == 0) ? bq : (z == 1) ? bk : bv;
  const int nbase = n0g & 1023;
  for (int n = 0; n < 4; ++n) {
    const int col = nbase + wn + n * 16 + cl;
    const float bval = bias[col];
    const int h = col >> 6, d = col & 63;
    for (int m = 0; m < 4; ++m) {
      const int rbase = m0 + wm + m * 16 + rg * 4;   // multiple of 4
      const int b = rbase >> 11, s = rbase & 2047;   // constant over r
      float v[4];
      for (int r = 0; r < 4; ++r) v[r] = acc[m][n][r] + bval;
      if (z == 0) {
        for (int r = 0; r < 4; ++r)
          Qs[((b * NH + h) * SEQ + s + r) * HD + d] =
              f2bf(v[r] * (0.125f * LOG2E));
      } else if (z == 1) {
        for (int r = 0; r < 4; ++r)
          Kb[((b * NH + h) * SEQ + s + r) * HD + d] = f2bf(v[r]);
      } else {
        // V: the 4 r-values are s-contiguous -> one 8B store
        u16x4 pk;
        for (int r = 0; r < 4; ++r) pk[r] = f2bf(v[r]);
        *reinterpret_cast<u16x4*>(&Vt[((b * NH + h) * HD + d) * SEQ + s]) = pk;
      }
    }
  }
}

// ---------- flash attention (unchanged from round 3) ----------
__global__ __launch_bounds__(256, 3) void attn_kernel(
    const unsigned short* __restrict__ Qs, const unsigned short* __restrict__ Kb,
    const unsigned short* __restrict__ Vt, const float* __restrict__ mask,
    float* __restrict__ out) {
  const int bid = blockIdx.x;
  const int lbid = (bid & 7) * 128 + (bid >> 3);
  const int head = lbid >> 4;
  const int qchunk = lbid & 15;
  const int b = head >> 4, h = head & 15;
  const int tid = threadIdx.x, lane = tid & 63, w = tid >> 6;
  const int q0 = qchunk * 128 + w * 32;
  const int cl = lane & 15, rg = lane >> 4;

  __shared__ unsigned short Kbuf[2][64 * 64];
  __shared__ unsigned short Vbuf[2][64 * 64];
  __shared__ __bf16 P[4][2][32][40];

  const int srow0 = tid >> 3, scl0 = tid & 7;
  const int srow1 = (256 + tid) >> 3, scl1 = tid & 7;
  const unsigned short* kg0 = Kb + (head * SEQ + srow0) * HD + ((scl0 ^ (srow0 & 7)) * 8);
  const unsigned short* kg1 = Kb + (head * SEQ + srow1) * HD + ((scl1 ^ (srow1 & 7)) * 8);
  const unsigned short* vg0 = Vt + (head * HD + srow0) * SEQ + ((scl0 ^ (srow0 & 7)) * 8);
  const unsigned short* vg1 = Vt + (head * HD + srow1) * SEQ + ((scl1 ^ (srow1 & 7)) * 8);

#define STAGE(buf, kk)                                                         \
  do {                                                                         \
    GLOAD_LDS16(kg0 + (size_t)(kk)*HD, &Kbuf[buf][tid * 8]);                   \
    GLOAD_LDS16(kg1 + (size_t)(kk)*HD, &Kbuf[buf][(256 + tid) * 8]);           \
    GLOAD_LDS16(vg0 + (kk), &Vbuf[buf][tid * 8]);                              \
    GLOAD_LDS16(vg1 + (kk), &Vbuf[buf][(256 + tid) * 8]);                      \
  } while (0)

  u16x8 qf[2][2];
  for (int rf = 0; rf < 2; ++rf)
    for (int dc = 0; dc < 2; ++dc)
      qf[rf][dc] = *reinterpret_cast<const u16x8*>(
          Qs + (head * SEQ + q0 + rf * 16 + cl) * HD + dc * 32 + rg * 8);

  f32x4 ctx[2][4] = {};
  float lrow[2][4] = {};

  STAGE(0, 0);
  __syncthreads();

  for (int t = 0; t < SEQ / 64; ++t) {
    const int cur = t & 1;
    const int kk = t * 64;
    if (t + 1 < SEQ / 64) STAGE(cur ^ 1, kk + 64);

    float mv[4];
    for (int cf = 0; cf < 4; ++cf)
      mv[cf] = mask[b * SEQ + kk + cf * 16 + cl] * LOG2E;

    f32x4 s[2][4] = {};
    for (int cf = 0; cf < 4; ++cf) {
      const int krow = cf * 16 + cl;
      u16x8 kf0 = *reinterpret_cast<const u16x8*>(
          &Kbuf[cur][krow * 64 + ((rg ^ (krow & 7)) * 8)]);
      u16x8 kf1 = *reinterpret_cast<const u16x8*>(
          &Kbuf[cur][krow * 64 + (((4 | rg) ^ (krow & 7)) * 8)]);
      for (int rf = 0; rf < 2; ++rf) {
        s[rf][cf] = mfma16(qf[rf][0], kf0, s[rf][cf]);
        s[rf][cf] = mfma16(qf[rf][1], kf1, s[rf][cf]);
      }
    }

    for (int jj = 0; jj < 2; ++jj) {
      for (int rf = 0; rf < 2; ++rf)
        for (int cc = 0; cc < 2; ++cc) {
          const int cf = jj * 2 + cc;
          for (int r = 0; r < 4; ++r) {
            float p = __builtin_amdgcn_exp2f(s[rf][cf][r] + mv[cf]);
            lrow[rf][r] += p;
            P[w][jj][rf * 16 + rg * 4 + r][cc * 16 + cl] = (__bf16)p;
          }
        }
      u16x8 pa[2];
      for (int rf = 0; rf < 2; ++rf)
        pa[rf] = *reinterpret_cast<const u16x8*>(&P[w][jj][rf * 16 + cl][rg * 8]);
      for (int df = 0; df < 4; ++df) {
        const int vrow = df * 16 + cl;
        u16x8 vf = *reinterpret_cast<const u16x8*>(
            &Vbuf[cur][vrow * 64 + ((((jj << 2) | rg) ^ (vrow & 7)) * 8)]);
        for (int rf = 0; rf < 2; ++rf)
          ctx[rf][df] = mfma16(pa[rf], vf, ctx[rf][df]);
      }
    }
    __syncthreads();
  }

  for (int rf = 0; rf < 2; ++rf)
    for (int off = 1; off < 16; off <<= 1)
      for (int r = 0; r < 4; ++r)
        lrow[rf][r] += __shfl_xor(lrow[rf][r], off);

  for (int rf = 0; rf < 2; ++rf) {
    float inv[4];
    for (int r = 0; r < 4; ++r) inv[r] = 1.0f / lrow[rf][r];
    for (int df = 0; df < 4; ++df)
      for (int r = 0; r < 4; ++r)
        out[(b * SEQ + q0 + rf * 16 + rg * 4 + r) * HDIM + h * HD + df * 16 + cl] =
            ctx[rf][df][r] * inv[r];
  }
#undef STAGE
}

extern "C" void kernel_launch(void* const* d_in, const int* in_sizes, int n_in,
                              void* d_out, int out_size, void* d_ws, size_t ws_size,
                              hipStream_t stream) {
  const float* hs   = (const float*)d_in[0];
  const float* mask = (const float*)d_in[1];
  // d_in[2] intent_ids, d_in[9..11] intent path: unused (softmax shift-invariant)
  const float* Wq = (const float*)d_in[3];
  const float* bq = (const float*)d_in[4];
  const float* Wk = (const float*)d_in[5];
  const float* bk = (const float*)d_in[6];
  const float* Wv = (const float*)d_in[7];
  const float* bv = (const float*)d_in[8];
  float* out = (float*)d_out;

  uint8_t* ws = (uint8_t*)d_ws;
  const size_t MB = 1024 * 1024;
  unsigned short* Xb   = (unsigned short*)(ws);            // 16 MB
  unsigned short* Wcat = (unsigned short*)(ws + 16 * MB);  // 6 MB: [3][1024][1024]
  unsigned short* Qsp  = (unsigned short*)(ws + 22 * MB);  // 16 MB: [64][2048][64]
  unsigned short* Kbp  = (unsigned short*)(ws + 38 * MB);  // 16 MB
  unsigned short* Vtp  = (unsigned short*)(ws + 54 * MB);  // 16 MB: [64][64][2048]

  cvt_x_kernel<<<4096, 256, 0, stream>>>(hs, Xb);
  cvt_wt_kernel<<<dim3(16, 16, 3), 256, 0, stream>>>(Wq, Wk, Wv, Wcat);
  proj_kernel<<<dim3(64, 24), 256, 0, stream>>>(Xb, Wcat, bq, bk, bv,
                                                Qsp, Kbp, Vtp);
  attn_kernel<<<1024, 256, 0, stream>>>(Qsp, Kbp, Vtp, mask, out);
}

// Round 6
// 179.603 us; speedup vs baseline: 1.2618x; 1.0686x over previous
//
#include <hip/hip_runtime.h>
#include <stdint.h>

#define NH    16
#define HD    64
#define HDIM  1024
#define BATCH 4
#define SEQ   2048

typedef __attribute__((ext_vector_type(4))) float f32x4;
typedef __attribute__((ext_vector_type(8))) __bf16 bf16x8;
typedef __attribute__((ext_vector_type(8))) unsigned short u16x8;
typedef __attribute__((ext_vector_type(4))) unsigned short u16x4;

#define LOG2E 1.44269504088896340736f

__device__ __forceinline__ unsigned short f2bf(float f) {
  unsigned int u = __builtin_bit_cast(unsigned int, f);
  u += 0x7fffu + ((u >> 16) & 1u);   // RNE
  return (unsigned short)(u >> 16);
}

__device__ __forceinline__ f32x4 mfma16(u16x8 a, u16x8 b, f32x4 c) {
  return __builtin_amdgcn_mfma_f32_16x16x32_bf16(
      __builtin_bit_cast(bf16x8, a), __builtin_bit_cast(bf16x8, b), c, 0, 0, 0);
}

#define GLOAD_LDS16(g, l)                                                      \
  __builtin_amdgcn_global_load_lds(                                            \
      (const __attribute__((address_space(1))) unsigned int*)(g),              \
      (__attribute__((address_space(3))) unsigned int*)(l), 16, 0, 0)

// ---------- fp32 -> bf16 bits, x8 vectorized ----------
__global__ __launch_bounds__(256) void cvt_x_kernel(
    const float* __restrict__ src, unsigned short* __restrict__ dst) {
  int i = (blockIdx.x * 256 + threadIdx.x) * 8;
  f32x4 a = *reinterpret_cast<const f32x4*>(src + i);
  f32x4 b = *reinterpret_cast<const f32x4*>(src + i + 4);
  u16x8 o;
  o[0] = f2bf(a[0]); o[1] = f2bf(a[1]); o[2] = f2bf(a[2]); o[3] = f2bf(a[3]);
  o[4] = f2bf(b[0]); o[5] = f2bf(b[1]); o[6] = f2bf(b[2]); o[7] = f2bf(b[3]);
  *reinterpret_cast<u16x8*>(dst + i) = o;
}

// ---------- W[k][n] fp32 -> Wcat[z][n][k] bf16, LDS-tiled transpose ----------
__global__ __launch_bounds__(256) void cvt_wt_kernel(
    const float* __restrict__ Wq, const float* __restrict__ Wk,
    const float* __restrict__ Wv, unsigned short* __restrict__ Wcat) {
  const float* __restrict__ src =
      (blockIdx.z == 0) ? Wq : (blockIdx.z == 1) ? Wk : Wv;
  unsigned short* __restrict__ dst = Wcat + (size_t)blockIdx.z * HDIM * HDIM;
  __shared__ float T[64][65];
  const int k0 = blockIdx.y * 64, n0 = blockIdx.x * 64;
  const int tid = threadIdx.x;
  const int lrow = tid >> 4, c4 = (tid & 15) * 4;
  for (int it = 0; it < 4; ++it) {
    f32x4 v = *reinterpret_cast<const f32x4*>(
        &src[(k0 + it * 16 + lrow) * HDIM + n0 + c4]);
    T[it * 16 + lrow][c4 + 0] = v[0];
    T[it * 16 + lrow][c4 + 1] = v[1];
    T[it * 16 + lrow][c4 + 2] = v[2];
    T[it * 16 + lrow][c4 + 3] = v[3];
  }
  __syncthreads();
  const int n = tid >> 2, kc = (tid & 3) * 16;
  u16x8 o0, o1;
  for (int j = 0; j < 8; ++j) o0[j] = f2bf(T[kc + j][n]);
  for (int j = 0; j < 8; ++j) o1[j] = f2bf(T[kc + 8 + j][n]);
  *reinterpret_cast<u16x8*>(&dst[(n0 + n) * HDIM + k0 + kc]) = o0;
  *reinterpret_cast<u16x8*>(&dst[(n0 + n) * HDIM + k0 + kc + 8]) = o1;
}

// ---------- fused QKV projection (unchanged from round 5) ----------
__global__ __launch_bounds__(256) void proj_kernel(
    const unsigned short* __restrict__ Xb,
    const unsigned short* __restrict__ Wcat,
    const float* __restrict__ bq, const float* __restrict__ bk,
    const float* __restrict__ bv,
    unsigned short* __restrict__ Qs, unsigned short* __restrict__ Kb,
    unsigned short* __restrict__ Vt) {
  const int m0 = blockIdx.x * 128;
  const int n0g = blockIdx.y * 128;
  __shared__ unsigned short As[2][128 * 64];
  __shared__ unsigned short Bs[2][128 * 64];
  const int tid = threadIdx.x, lane = tid & 63, w = tid >> 6;
  const int wm = (w >> 1) * 64, wn = (w & 1) * 64;
  const int cl = lane & 15, rg = lane >> 4;
  f32x4 acc[4][4] = {};

#define PSTAGE(buf, k0)                                                        \
  do {                                                                         \
    for (int p = 0; p < 4; ++p) {                                              \
      int c = p * 256 + tid, row = c >> 3, ch = c & 7;                         \
      int sch = (ch ^ (row & 7)) * 8;                                          \
      GLOAD_LDS16(Xb + (m0 + row) * HDIM + (k0) + sch, &As[buf][c * 8]);       \
      GLOAD_LDS16(Wcat + (size_t)(n0g + row) * HDIM + (k0) + sch,              \
                  &Bs[buf][c * 8]);                                            \
    }                                                                          \
  } while (0)

  PSTAGE(0, 0);
  __syncthreads();
  for (int kt = 0; kt < HDIM / 64; ++kt) {
    const int cur = kt & 1;
    if (kt + 1 < HDIM / 64) PSTAGE(cur ^ 1, (kt + 1) * 64);
    for (int ks = 0; ks < 2; ++ks) {
      u16x8 af[4], bfr[4];
      for (int m = 0; m < 4; ++m) {
        const int row = wm + m * 16 + cl;
        af[m] = *reinterpret_cast<const u16x8*>(
            &As[cur][row * 64 + (((ks * 4 + rg) ^ (row & 7)) * 8)]);
      }
      for (int n = 0; n < 4; ++n) {
        const int row = wn + n * 16 + cl;
        bfr[n] = *reinterpret_cast<const u16x8*>(
            &Bs[cur][row * 64 + (((ks * 4 + rg) ^ (row & 7)) * 8)]);
      }
      for (int m = 0; m < 4; ++m)
        for (int n = 0; n < 4; ++n)
          acc[m][n] = mfma16(af[m], bfr[n], acc[m][n]);
    }
    __syncthreads();
  }
#undef PSTAGE

  const int z = n0g >> 10;
  const float* __restrict__ bias = (z == 0) ? bq : (z == 1) ? bk : bv;
  const int nbase = n0g & 1023;
  for (int n = 0; n < 4; ++n) {
    const int col = nbase + wn + n * 16 + cl;
    const float bval = bias[col];
    const int h = col >> 6, d = col & 63;
    for (int m = 0; m < 4; ++m) {
      const int rbase = m0 + wm + m * 16 + rg * 4;
      const int b = rbase >> 11, s = rbase & 2047;
      float v[4];
      for (int r = 0; r < 4; ++r) v[r] = acc[m][n][r] + bval;
      if (z == 0) {
        for (int r = 0; r < 4; ++r)
          Qs[((b * NH + h) * SEQ + s + r) * HD + d] =
              f2bf(v[r] * (0.125f * LOG2E));
      } else if (z == 1) {
        for (int r = 0; r < 4; ++r)
          Kb[((b * NH + h) * SEQ + s + r) * HD + d] = f2bf(v[r]);
      } else {
        u16x4 pk;
        for (int r = 0; r < 4; ++r) pk[r] = f2bf(v[r]);
        *reinterpret_cast<u16x4*>(&Vt[((b * NH + h) * HD + d) * SEQ + s]) = pk;
      }
    }
  }
}

// ---------- flash attention v3: swapped-QK, P fully in-register ----------
// sT = mfma(A=K-frag, B=Q-frag) -> D[key=rg*4+r][q=cl]: each lane holds
// P[q=cl][...] lane-locally. A-row->key permutation kappa(c,i) =
// (i>>2)*8 + c*4 + (i&3) makes the lane's 16 keys per (jj) exactly the
// 8-contiguous chunks rg*8..rg*8+7 that the PV A-fragment needs -> P is
// packed to bf16 entirely in-register (no LDS roundtrip, no cross-lane).
// Bank swizzle SWZ(row) = ((row&3)<<1)|((row>>3)&1) keeps both the
// kappa-permuted K reads and the V reads at free 2-way (8 slots x 2 lanes).
// Mask staged to LDS once (broadcast reads). LDS = 16+16+8 = 40KB ->
// 4 blocks/CU: the whole 1024-block grid is co-resident.
#define SWZ(row) ((((row) & 3) << 1) | (((row) >> 3) & 1))
__global__ __launch_bounds__(256, 4) void attn_kernel(
    const unsigned short* __restrict__ Qs, const unsigned short* __restrict__ Kb,
    const unsigned short* __restrict__ Vt, const float* __restrict__ mask,
    float* __restrict__ out) {
  const int bid = blockIdx.x;
  const int lbid = (bid & 7) * 128 + (bid >> 3);
  const int head = lbid >> 4;
  const int qchunk = lbid & 15;
  const int b = head >> 4, h = head & 15;
  const int tid = threadIdx.x, lane = tid & 63, w = tid >> 6;
  const int q0 = qchunk * 128 + w * 32;
  const int cl = lane & 15, rg = lane >> 4;

  __shared__ unsigned short Kbuf[2][64 * 64];  // 16 KB [key][d], SWZ chunks
  __shared__ unsigned short Vbuf[2][64 * 64];  // 16 KB [d][key], SWZ chunks
  __shared__ float Mlds[SEQ];                  // 8 KB mask*LOG2E

  // stage mask row for this batch (once)
  {
    const float* mrow = mask + b * SEQ;
    f32x4 m0 = *reinterpret_cast<const f32x4*>(mrow + tid * 8);
    f32x4 m1 = *reinterpret_cast<const f32x4*>(mrow + tid * 8 + 4);
    for (int j = 0; j < 4; ++j) {
      Mlds[tid * 8 + j] = m0[j] * LOG2E;
      Mlds[tid * 8 + 4 + j] = m1[j] * LOG2E;
    }
  }

  const int srow0 = tid >> 3, ch0 = tid & 7;
  const int srow1 = 32 + srow0;
  const unsigned short* kgA = Kb + (head * SEQ + srow0) * HD + ((ch0 ^ SWZ(srow0)) * 8);
  const unsigned short* kgB = Kb + (head * SEQ + srow1) * HD + ((ch0 ^ SWZ(srow1)) * 8);
  const unsigned short* vgA = Vt + (head * HD + srow0) * SEQ + ((ch0 ^ SWZ(srow0)) * 8);
  const unsigned short* vgB = Vt + (head * HD + srow1) * SEQ + ((ch0 ^ SWZ(srow1)) * 8);

#define STAGE(buf, kk)                                                         \
  do {                                                                         \
    GLOAD_LDS16(kgA + (size_t)(kk)*HD, &Kbuf[buf][tid * 8]);                   \
    GLOAD_LDS16(kgB + (size_t)(kk)*HD, &Kbuf[buf][(256 + tid) * 8]);           \
    GLOAD_LDS16(vgA + (kk), &Vbuf[buf][tid * 8]);                              \
    GLOAD_LDS16(vgB + (kk), &Vbuf[buf][(256 + tid) * 8]);                      \
  } while (0)

  u16x8 qf[2][2];
  for (int rf = 0; rf < 2; ++rf)
    for (int dc = 0; dc < 2; ++dc)
      qf[rf][dc] = *reinterpret_cast<const u16x8*>(
          Qs + (head * SEQ + q0 + rf * 16 + cl) * HD + dc * 32 + rg * 8);

  f32x4 ctx[2][4] = {};
  float lrow[2] = {0.f, 0.f};

  STAGE(0, 0);
  __syncthreads();

  for (int t = 0; t < SEQ / 64; ++t) {
    const int cur = t & 1;
    const int kk = t * 64;
    if (t + 1 < SEQ / 64) STAGE(cur ^ 1, kk + 64);

    for (int jj = 0; jj < 2; ++jj) {
      // QK^T swapped: sT[c][rf], D[key' = rg*4+r][q = cl]
      f32x4 sT[2][2] = {};
      for (int c = 0; c < 2; ++c) {
        const int krow = jj * 32 + ((cl >> 2) << 3) + (c << 2) + (cl & 3);
        u16x8 kf0 = *reinterpret_cast<const u16x8*>(
            &Kbuf[cur][krow * 64 + ((rg ^ SWZ(krow)) * 8)]);
        u16x8 kf1 = *reinterpret_cast<const u16x8*>(
            &Kbuf[cur][krow * 64 + (((4 | rg) ^ SWZ(krow)) * 8)]);
        for (int rf = 0; rf < 2; ++rf) {
          sT[c][rf] = mfma16(kf0, qf[rf][0], sT[c][rf]);
          sT[c][rf] = mfma16(kf1, qf[rf][1], sT[c][rf]);
        }
      }
      // softmax (exp2 domain) + in-register pack: lane's key for (c,r) is
      // kk + jj*32 + rg*8 + c*4 + r  ->  pa elem index c*4+r
      u16x8 pa[2];
      for (int rf = 0; rf < 2; ++rf)
        for (int c = 0; c < 2; ++c) {
          f32x4 mv = *reinterpret_cast<const f32x4*>(
              &Mlds[kk + jj * 32 + rg * 8 + c * 4]);
          for (int r = 0; r < 4; ++r) {
            float p = __builtin_amdgcn_exp2f(sT[c][rf][r] + mv[r]);
            lrow[rf] += p;
            pa[rf][c * 4 + r] = f2bf(p);
          }
        }
      // PV: pa is the A-fragment directly
      for (int df = 0; df < 4; ++df) {
        const int vrow = df * 16 + cl;
        u16x8 vf = *reinterpret_cast<const u16x8*>(
            &Vbuf[cur][vrow * 64 + (((jj * 4 + rg) ^ SWZ(vrow)) * 8)]);
        for (int rf = 0; rf < 2; ++rf)
          ctx[rf][df] = mfma16(pa[rf], vf, ctx[rf][df]);
      }
    }
    __syncthreads();
  }

  // lrow at lane (cl,rg) holds partial for q-row rf*16+cl over this lane's
  // keys; reduce across rg groups (lane bits 4,5), then redistribute to the
  // ctx row layout (q-row = rg*4+r) via per-lane shfl gather.
  for (int rf = 0; rf < 2; ++rf) {
    lrow[rf] += __shfl_xor(lrow[rf], 16);
    lrow[rf] += __shfl_xor(lrow[rf], 32);
  }
  for (int rf = 0; rf < 2; ++rf) {
    float inv[4];
    for (int r = 0; r < 4; ++r)
      inv[r] = 1.0f / __shfl(lrow[rf], rg * 4 + r);
    for (int df = 0; df < 4; ++df)
      for (int r = 0; r < 4; ++r)
        out[(b * SEQ + q0 + rf * 16 + rg * 4 + r) * HDIM + h * HD + df * 16 + cl] =
            ctx[rf][df][r] * inv[r];
  }
#undef STAGE
}

extern "C" void kernel_launch(void* const* d_in, const int* in_sizes, int n_in,
                              void* d_out, int out_size, void* d_ws, size_t ws_size,
                              hipStream_t stream) {
  const float* hs   = (const float*)d_in[0];
  const float* mask = (const float*)d_in[1];
  // d_in[2] intent_ids, d_in[9..11] intent path: unused (softmax shift-invariant)
  const float* Wq = (const float*)d_in[3];
  const float* bq = (const float*)d_in[4];
  const float* Wk = (const float*)d_in[5];
  const float* bk = (const float*)d_in[6];
  const float* Wv = (const float*)d_in[7];
  const float* bv = (const float*)d_in[8];
  float* out = (float*)d_out;

  uint8_t* ws = (uint8_t*)d_ws;
  const size_t MB = 1024 * 1024;
  unsigned short* Xb   = (unsigned short*)(ws);            // 16 MB
  unsigned short* Wcat = (unsigned short*)(ws + 16 * MB);  // 6 MB: [3][1024][1024]
  unsigned short* Qsp  = (unsigned short*)(ws + 22 * MB);  // 16 MB: [64][2048][64]
  unsigned short* Kbp  = (unsigned short*)(ws + 38 * MB);  // 16 MB
  unsigned short* Vtp  = (unsigned short*)(ws + 54 * MB);  // 16 MB: [64][64][2048]

  cvt_x_kernel<<<4096, 256, 0, stream>>>(hs, Xb);
  cvt_wt_kernel<<<dim3(16, 16, 3), 256, 0, stream>>>(Wq, Wk, Wv, Wcat);
  proj_kernel<<<dim3(64, 24), 256, 0, stream>>>(Xb, Wcat, bq, bk, bv,
                                                Qsp, Kbp, Vtp);
  attn_kernel<<<1024, 256, 0, stream>>>(Qsp, Kbp, Vtp, mask, out);
}

// Round 7
// 161.131 us; speedup vs baseline: 1.4064x; 1.1146x over previous
//
#include <hip/hip_runtime.h>
#include <stdint.h>

#define NH    16
#define HD    64
#define HDIM  1024
#define BATCH 4
#define SEQ   2048

typedef __attribute__((ext_vector_type(4))) float f32x4;
typedef __attribute__((ext_vector_type(8))) __bf16 bf16x8;
typedef __attribute__((ext_vector_type(8))) unsigned short u16x8;
typedef __attribute__((ext_vector_type(4))) unsigned short u16x4;

#define LOG2E 1.44269504088896340736f

__device__ __forceinline__ unsigned short f2bf(float f) {
  unsigned int u = __builtin_bit_cast(unsigned int, f);
  u += 0x7fffu + ((u >> 16) & 1u);   // RNE
  return (unsigned short)(u >> 16);
}

__device__ __forceinline__ f32x4 mfma16(u16x8 a, u16x8 b, f32x4 c) {
  return __builtin_amdgcn_mfma_f32_16x16x32_bf16(
      __builtin_bit_cast(bf16x8, a), __builtin_bit_cast(bf16x8, b), c, 0, 0, 0);
}

__device__ __forceinline__ f32x4 mfma16b(bf16x8 a, u16x8 b, f32x4 c) {
  return __builtin_amdgcn_mfma_f32_16x16x32_bf16(
      a, __builtin_bit_cast(bf16x8, b), c, 0, 0, 0);
}

#define GLOAD_LDS16(g, l)                                                      \
  __builtin_amdgcn_global_load_lds(                                            \
      (const __attribute__((address_space(1))) unsigned int*)(g),              \
      (__attribute__((address_space(3))) unsigned int*)(l), 16, 0, 0)

// ---------- fp32 -> bf16 bits, x8 vectorized ----------
__global__ __launch_bounds__(256) void cvt_x_kernel(
    const float* __restrict__ src, unsigned short* __restrict__ dst) {
  int i = (blockIdx.x * 256 + threadIdx.x) * 8;
  f32x4 a = *reinterpret_cast<const f32x4*>(src + i);
  f32x4 b = *reinterpret_cast<const f32x4*>(src + i + 4);
  u16x8 o;
  o[0] = f2bf(a[0]); o[1] = f2bf(a[1]); o[2] = f2bf(a[2]); o[3] = f2bf(a[3]);
  o[4] = f2bf(b[0]); o[5] = f2bf(b[1]); o[6] = f2bf(b[2]); o[7] = f2bf(b[3]);
  *reinterpret_cast<u16x8*>(dst + i) = o;
}

// ---------- W[k][n] fp32 -> Wcat[z][n][k] bf16, LDS-tiled transpose ----------
__global__ __launch_bounds__(256) void cvt_wt_kernel(
    const float* __restrict__ Wq, const float* __restrict__ Wk,
    const float* __restrict__ Wv, unsigned short* __restrict__ Wcat) {
  const float* __restrict__ src =
      (blockIdx.z == 0) ? Wq : (blockIdx.z == 1) ? Wk : Wv;
  unsigned short* __restrict__ dst = Wcat + (size_t)blockIdx.z * HDIM * HDIM;
  __shared__ float T[64][65];
  const int k0 = blockIdx.y * 64, n0 = blockIdx.x * 64;
  const int tid = threadIdx.x;
  const int lrow = tid >> 4, c4 = (tid & 15) * 4;
  for (int it = 0; it < 4; ++it) {
    f32x4 v = *reinterpret_cast<const f32x4*>(
        &src[(k0 + it * 16 + lrow) * HDIM + n0 + c4]);
    T[it * 16 + lrow][c4 + 0] = v[0];
    T[it * 16 + lrow][c4 + 1] = v[1];
    T[it * 16 + lrow][c4 + 2] = v[2];
    T[it * 16 + lrow][c4 + 3] = v[3];
  }
  __syncthreads();
  const int n = tid >> 2, kc = (tid & 3) * 16;
  u16x8 o0, o1;
  for (int j = 0; j < 8; ++j) o0[j] = f2bf(T[kc + j][n]);
  for (int j = 0; j < 8; ++j) o1[j] = f2bf(T[kc + 8 + j][n]);
  *reinterpret_cast<u16x8*>(&dst[(n0 + n) * HDIM + k0 + kc]) = o0;
  *reinterpret_cast<u16x8*>(&dst[(n0 + n) * HDIM + k0 + kc + 8]) = o1;
}

// ---------- fused QKV projection (unchanged from round 5) ----------
__global__ __launch_bounds__(256) void proj_kernel(
    const unsigned short* __restrict__ Xb,
    const unsigned short* __restrict__ Wcat,
    const float* __restrict__ bq, const float* __restrict__ bk,
    const float* __restrict__ bv,
    unsigned short* __restrict__ Qs, unsigned short* __restrict__ Kb,
    unsigned short* __restrict__ Vt) {
  const int m0 = blockIdx.x * 128;
  const int n0g = blockIdx.y * 128;
  __shared__ unsigned short As[2][128 * 64];
  __shared__ unsigned short Bs[2][128 * 64];
  const int tid = threadIdx.x, lane = tid & 63, w = tid >> 6;
  const int wm = (w >> 1) * 64, wn = (w & 1) * 64;
  const int cl = lane & 15, rg = lane >> 4;
  f32x4 acc[4][4] = {};

#define PSTAGE(buf, k0)                                                        \
  do {                                                                         \
    for (int p = 0; p < 4; ++p) {                                              \
      int c = p * 256 + tid, row = c >> 3, ch = c & 7;                         \
      int sch = (ch ^ (row & 7)) * 8;                                          \
      GLOAD_LDS16(Xb + (m0 + row) * HDIM + (k0) + sch, &As[buf][c * 8]);       \
      GLOAD_LDS16(Wcat + (size_t)(n0g + row) * HDIM + (k0) + sch,              \
                  &Bs[buf][c * 8]);                                            \
    }                                                                          \
  } while (0)

  PSTAGE(0, 0);
  __syncthreads();
  for (int kt = 0; kt < HDIM / 64; ++kt) {
    const int cur = kt & 1;
    if (kt + 1 < HDIM / 64) PSTAGE(cur ^ 1, (kt + 1) * 64);
    for (int ks = 0; ks < 2; ++ks) {
      u16x8 af[4], bfr[4];
      for (int m = 0; m < 4; ++m) {
        const int row = wm + m * 16 + cl;
        af[m] = *reinterpret_cast<const u16x8*>(
            &As[cur][row * 64 + (((ks * 4 + rg) ^ (row & 7)) * 8)]);
      }
      for (int n = 0; n < 4; ++n) {
        const int row = wn + n * 16 + cl;
        bfr[n] = *reinterpret_cast<const u16x8*>(
            &Bs[cur][row * 64 + (((ks * 4 + rg) ^ (row & 7)) * 8)]);
      }
      for (int m = 0; m < 4; ++m)
        for (int n = 0; n < 4; ++n)
          acc[m][n] = mfma16(af[m], bfr[n], acc[m][n]);
    }
    __syncthreads();
  }
#undef PSTAGE

  const int z = n0g >> 10;
  const float* __restrict__ bias = (z == 0) ? bq : (z == 1) ? bk : bv;
  const int nbase = n0g & 1023;
  for (int n = 0; n < 4; ++n) {
    const int col = nbase + wn + n * 16 + cl;
    const float bval = bias[col];
    const int h = col >> 6, d = col & 63;
    for (int m = 0; m < 4; ++m) {
      const int rbase = m0 + wm + m * 16 + rg * 4;
      const int b = rbase >> 11, s = rbase & 2047;
      float v[4];
      for (int r = 0; r < 4; ++r) v[r] = acc[m][n][r] + bval;
      if (z == 0) {
        for (int r = 0; r < 4; ++r)
          Qs[((b * NH + h) * SEQ + s + r) * HD + d] =
              f2bf(v[r] * (0.125f * LOG2E));
      } else if (z == 1) {
        for (int r = 0; r < 4; ++r)
          Kb[((b * NH + h) * SEQ + s + r) * HD + d] = f2bf(v[r]);
      } else {
        u16x4 pk;
        for (int r = 0; r < 4; ++r) pk[r] = f2bf(v[r]);
        *reinterpret_cast<u16x4*>(&Vt[((b * NH + h) * HD + d) * SEQ + s]) = pk;
      }
    }
  }
}

// ---------- flash attention v4: swapped-QK, P in-register, VALU-lean ----------
// vs v3: (1) mask folded into the QK MFMA C-operand (C-init = mask vector,
// exact f32 accumulate) -- kills 32 v_add + half the Mlds reads per tile;
// (2) P pack via native (__bf16) casts -> compiler emits v_cvt_pk_bf16_f32
// pairs (m240) instead of hand-rolled 3-op RNE; (3) T5 s_setprio(1) around
// the QK and PV MFMA clusters (independent-phase waves, m191 regime).
#define SWZ(row) ((((row) & 3) << 1) | (((row) >> 3) & 1))
__global__ __launch_bounds__(256, 4) void attn_kernel(
    const unsigned short* __restrict__ Qs, const unsigned short* __restrict__ Kb,
    const unsigned short* __restrict__ Vt, const float* __restrict__ mask,
    float* __restrict__ out) {
  const int bid = blockIdx.x;
  const int lbid = (bid & 7) * 128 + (bid >> 3);
  const int head = lbid >> 4;
  const int qchunk = lbid & 15;
  const int b = head >> 4, h = head & 15;
  const int tid = threadIdx.x, lane = tid & 63, w = tid >> 6;
  const int q0 = qchunk * 128 + w * 32;
  const int cl = lane & 15, rg = lane >> 4;

  __shared__ unsigned short Kbuf[2][64 * 64];  // 16 KB [key][d], SWZ chunks
  __shared__ unsigned short Vbuf[2][64 * 64];  // 16 KB [d][key], SWZ chunks
  __shared__ float Mlds[SEQ];                  // 8 KB mask*LOG2E

  {
    const float* mrow = mask + b * SEQ;
    f32x4 m0 = *reinterpret_cast<const f32x4*>(mrow + tid * 8);
    f32x4 m1 = *reinterpret_cast<const f32x4*>(mrow + tid * 8 + 4);
    for (int j = 0; j < 4; ++j) {
      Mlds[tid * 8 + j] = m0[j] * LOG2E;
      Mlds[tid * 8 + 4 + j] = m1[j] * LOG2E;
    }
  }

  const int srow0 = tid >> 3, ch0 = tid & 7;
  const int srow1 = 32 + srow0;
  const unsigned short* kgA = Kb + (head * SEQ + srow0) * HD + ((ch0 ^ SWZ(srow0)) * 8);
  const unsigned short* kgB = Kb + (head * SEQ + srow1) * HD + ((ch0 ^ SWZ(srow1)) * 8);
  const unsigned short* vgA = Vt + (head * HD + srow0) * SEQ + ((ch0 ^ SWZ(srow0)) * 8);
  const unsigned short* vgB = Vt + (head * HD + srow1) * SEQ + ((ch0 ^ SWZ(srow1)) * 8);

#define STAGE(buf, kk)                                                         \
  do {                                                                         \
    GLOAD_LDS16(kgA + (size_t)(kk)*HD, &Kbuf[buf][tid * 8]);                   \
    GLOAD_LDS16(kgB + (size_t)(kk)*HD, &Kbuf[buf][(256 + tid) * 8]);           \
    GLOAD_LDS16(vgA + (kk), &Vbuf[buf][tid * 8]);                              \
    GLOAD_LDS16(vgB + (kk), &Vbuf[buf][(256 + tid) * 8]);                      \
  } while (0)

  u16x8 qf[2][2];
  for (int rf = 0; rf < 2; ++rf)
    for (int dc = 0; dc < 2; ++dc)
      qf[rf][dc] = *reinterpret_cast<const u16x8*>(
          Qs + (head * SEQ + q0 + rf * 16 + cl) * HD + dc * 32 + rg * 8);

  f32x4 ctx[2][4] = {};
  float lrow[2] = {0.f, 0.f};

  STAGE(0, 0);
  __syncthreads();

  for (int t = 0; t < SEQ / 64; ++t) {
    const int cur = t & 1;
    const int kk = t * 64;
    if (t + 1 < SEQ / 64) STAGE(cur ^ 1, kk + 64);

    for (int jj = 0; jj < 2; ++jj) {
      // mask vectors for this lane's keys (kk + jj*32 + rg*8 + c*4 + r)
      f32x4 mv0 = *reinterpret_cast<const f32x4*>(&Mlds[kk + jj * 32 + rg * 8]);
      f32x4 mv1 = *reinterpret_cast<const f32x4*>(&Mlds[kk + jj * 32 + rg * 8 + 4]);
      // QK^T swapped, mask pre-loaded into the accumulator (C-in)
      f32x4 sT[2][2];
      sT[0][0] = mv0; sT[0][1] = mv0;
      sT[1][0] = mv1; sT[1][1] = mv1;
      __builtin_amdgcn_s_setprio(1);
      for (int c = 0; c < 2; ++c) {
        const int krow = jj * 32 + ((cl >> 2) << 3) + (c << 2) + (cl & 3);
        u16x8 kf0 = *reinterpret_cast<const u16x8*>(
            &Kbuf[cur][krow * 64 + ((rg ^ SWZ(krow)) * 8)]);
        u16x8 kf1 = *reinterpret_cast<const u16x8*>(
            &Kbuf[cur][krow * 64 + (((4 | rg) ^ SWZ(krow)) * 8)]);
        for (int rf = 0; rf < 2; ++rf) {
          sT[c][rf] = mfma16(kf0, qf[rf][0], sT[c][rf]);
          sT[c][rf] = mfma16(kf1, qf[rf][1], sT[c][rf]);
        }
      }
      __builtin_amdgcn_s_setprio(0);
      // softmax (exp2 domain) + in-register pack via native casts
      // (compiler fuses pairs into v_cvt_pk_bf16_f32)
      bf16x8 pa[2];
      for (int rf = 0; rf < 2; ++rf)
        for (int c = 0; c < 2; ++c)
          for (int r = 0; r < 4; ++r) {
            float p = __builtin_amdgcn_exp2f(sT[c][rf][r]);
            lrow[rf] += p;
            pa[rf][c * 4 + r] = (__bf16)p;
          }
      // PV: pa is the A-fragment directly
      __builtin_amdgcn_s_setprio(1);
      for (int df = 0; df < 4; ++df) {
        const int vrow = df * 16 + cl;
        u16x8 vf = *reinterpret_cast<const u16x8*>(
            &Vbuf[cur][vrow * 64 + (((jj * 4 + rg) ^ SWZ(vrow)) * 8)]);
        for (int rf = 0; rf < 2; ++rf)
          ctx[rf][df] = mfma16b(pa[rf], vf, ctx[rf][df]);
      }
      __builtin_amdgcn_s_setprio(0);
    }
    __syncthreads();
  }

  for (int rf = 0; rf < 2; ++rf) {
    lrow[rf] += __shfl_xor(lrow[rf], 16);
    lrow[rf] += __shfl_xor(lrow[rf], 32);
  }
  for (int rf = 0; rf < 2; ++rf) {
    float inv[4];
    for (int r = 0; r < 4; ++r)
      inv[r] = 1.0f / __shfl(lrow[rf], rg * 4 + r);
    for (int df = 0; df < 4; ++df)
      for (int r = 0; r < 4; ++r)
        out[(b * SEQ + q0 + rf * 16 + rg * 4 + r) * HDIM + h * HD + df * 16 + cl] =
            ctx[rf][df][r] * inv[r];
  }
#undef STAGE
}

extern "C" void kernel_launch(void* const* d_in, const int* in_sizes, int n_in,
                              void* d_out, int out_size, void* d_ws, size_t ws_size,
                              hipStream_t stream) {
  const float* hs   = (const float*)d_in[0];
  const float* mask = (const float*)d_in[1];
  // d_in[2] intent_ids, d_in[9..11] intent path: unused (softmax shift-invariant)
  const float* Wq = (const float*)d_in[3];
  const float* bq = (const float*)d_in[4];
  const float* Wk = (const float*)d_in[5];
  const float* bk = (const float*)d_in[6];
  const float* Wv = (const float*)d_in[7];
  const float* bv = (const float*)d_in[8];
  float* out = (float*)d_out;

  uint8_t* ws = (uint8_t*)d_ws;
  const size_t MB = 1024 * 1024;
  unsigned short* Xb   = (unsigned short*)(ws);            // 16 MB
  unsigned short* Wcat = (unsigned short*)(ws + 16 * MB);  // 6 MB: [3][1024][1024]
  unsigned short* Qsp  = (unsigned short*)(ws + 22 * MB);  // 16 MB: [64][2048][64]
  unsigned short* Kbp  = (unsigned short*)(ws + 38 * MB);  // 16 MB
  unsigned short* Vtp  = (unsigned short*)(ws + 54 * MB);  // 16 MB: [64][64][2048]

  cvt_x_kernel<<<4096, 256, 0, stream>>>(hs, Xb);
  cvt_wt_kernel<<<dim3(16, 16, 3), 256, 0, stream>>>(Wq, Wk, Wv, Wcat);
  proj_kernel<<<dim3(64, 24), 256, 0, stream>>>(Xb, Wcat, bq, bk, bv,
                                                Qsp, Kbp, Vtp);
  attn_kernel<<<1024, 256, 0, stream>>>(Qsp, Kbp, Vtp, mask, out);
}

// Round 8
// 160.826 us; speedup vs baseline: 1.4091x; 1.0019x over previous
//
#include <hip/hip_runtime.h>
#include <stdint.h>

#define NH    16
#define HD    64
#define HDIM  1024
#define BATCH 4
#define SEQ   2048

typedef __attribute__((ext_vector_type(4))) float f32x4;
typedef __attribute__((ext_vector_type(8))) __bf16 bf16x8;
typedef __attribute__((ext_vector_type(8))) unsigned short u16x8;
typedef __attribute__((ext_vector_type(4))) unsigned short u16x4;

#define LOG2E 1.44269504088896340736f

__device__ __forceinline__ unsigned short f2bf(float f) {
  unsigned int u = __builtin_bit_cast(unsigned int, f);
  u += 0x7fffu + ((u >> 16) & 1u);   // RNE
  return (unsigned short)(u >> 16);
}

__device__ __forceinline__ f32x4 mfma16(u16x8 a, u16x8 b, f32x4 c) {
  return __builtin_amdgcn_mfma_f32_16x16x32_bf16(
      __builtin_bit_cast(bf16x8, a), __builtin_bit_cast(bf16x8, b), c, 0, 0, 0);
}

__device__ __forceinline__ f32x4 mfma16b(bf16x8 a, u16x8 b, f32x4 c) {
  return __builtin_amdgcn_mfma_f32_16x16x32_bf16(
      a, __builtin_bit_cast(bf16x8, b), c, 0, 0, 0);
}

#define GLOAD_LDS16(g, l)                                                      \
  __builtin_amdgcn_global_load_lds(                                            \
      (const __attribute__((address_space(1))) unsigned int*)(g),              \
      (__attribute__((address_space(3))) unsigned int*)(l), 16, 0, 0)

// ---------- fp32 -> bf16 bits, x8 vectorized ----------
__global__ __launch_bounds__(256) void cvt_x_kernel(
    const float* __restrict__ src, unsigned short* __restrict__ dst) {
  int i = (blockIdx.x * 256 + threadIdx.x) * 8;
  f32x4 a = *reinterpret_cast<const f32x4*>(src + i);
  f32x4 b = *reinterpret_cast<const f32x4*>(src + i + 4);
  u16x8 o;
  o[0] = f2bf(a[0]); o[1] = f2bf(a[1]); o[2] = f2bf(a[2]); o[3] = f2bf(a[3]);
  o[4] = f2bf(b[0]); o[5] = f2bf(b[1]); o[6] = f2bf(b[2]); o[7] = f2bf(b[3]);
  *reinterpret_cast<u16x8*>(dst + i) = o;
}

// ---------- W[k][n] fp32 -> Wcat[z][n][k] bf16, LDS-tiled transpose ----------
__global__ __launch_bounds__(256) void cvt_wt_kernel(
    const float* __restrict__ Wq, const float* __restrict__ Wk,
    const float* __restrict__ Wv, unsigned short* __restrict__ Wcat) {
  const float* __restrict__ src =
      (blockIdx.z == 0) ? Wq : (blockIdx.z == 1) ? Wk : Wv;
  unsigned short* __restrict__ dst = Wcat + (size_t)blockIdx.z * HDIM * HDIM;
  __shared__ float T[64][65];
  const int k0 = blockIdx.y * 64, n0 = blockIdx.x * 64;
  const int tid = threadIdx.x;
  const int lrow = tid >> 4, c4 = (tid & 15) * 4;
  for (int it = 0; it < 4; ++it) {
    f32x4 v = *reinterpret_cast<const f32x4*>(
        &src[(k0 + it * 16 + lrow) * HDIM + n0 + c4]);
    T[it * 16 + lrow][c4 + 0] = v[0];
    T[it * 16 + lrow][c4 + 1] = v[1];
    T[it * 16 + lrow][c4 + 2] = v[2];
    T[it * 16 + lrow][c4 + 3] = v[3];
  }
  __syncthreads();
  const int n = tid >> 2, kc = (tid & 3) * 16;
  u16x8 o0, o1;
  for (int j = 0; j < 8; ++j) o0[j] = f2bf(T[kc + j][n]);
  for (int j = 0; j < 8; ++j) o1[j] = f2bf(T[kc + 8 + j][n]);
  *reinterpret_cast<u16x8*>(&dst[(n0 + n) * HDIM + k0 + kc]) = o0;
  *reinterpret_cast<u16x8*>(&dst[(n0 + n) * HDIM + k0 + kc + 8]) = o1;
}

// ---------- fused QKV projection: [8192x1024] @ [1024x3072] ----------
// v3: BK=32 double-buffered -> LDS 32 KB -> 4 blocks/CU (m132 lesson: the
// BK=64 dbuf's 64 KB capped residency at 2 blocks/CU = the 554 TF ceiling).
// Conflict-free swizzle for 64B rows (4 chunks): physical chunk
// c = ch ^ ((row>>1)&3); 16B-slot = (4*row + c) mod 8 covers all 8 slots
// x2 lanes over 16 consecutive rows (free 2-way). Rule #21 both-sides:
// linear gload_lds dest + inverse-swizzled global source + swizzled ds_read.
__global__ __launch_bounds__(256, 4) void proj_kernel(
    const unsigned short* __restrict__ Xb,
    const unsigned short* __restrict__ Wcat,
    const float* __restrict__ bq, const float* __restrict__ bk,
    const float* __restrict__ bv,
    unsigned short* __restrict__ Qs, unsigned short* __restrict__ Kb,
    unsigned short* __restrict__ Vt) {
  const int m0 = blockIdx.x * 128;
  const int n0g = blockIdx.y * 128;
  __shared__ unsigned short As[2][128 * 32];   // 8 KB each buf
  __shared__ unsigned short Bs[2][128 * 32];
  const int tid = threadIdx.x, lane = tid & 63, w = tid >> 6;
  const int wm = (w >> 1) * 64, wn = (w & 1) * 64;
  const int cl = lane & 15, rg = lane >> 4;
  f32x4 acc[4][4] = {};

  // 512 chunks of 16B per matrix per K-step; 2 per thread per matrix
#define PSTAGE(buf, k0)                                                        \
  do {                                                                         \
    for (int p = 0; p < 2; ++p) {                                              \
      int c = p * 256 + tid, row = c >> 2, ch = c & 3;                         \
      int sch = (ch ^ ((row >> 1) & 3)) * 8;                                   \
      GLOAD_LDS16(Xb + (m0 + row) * HDIM + (k0) + sch, &As[buf][c * 8]);       \
      GLOAD_LDS16(Wcat + (size_t)(n0g + row) * HDIM + (k0) + sch,              \
                  &Bs[buf][c * 8]);                                            \
    }                                                                          \
  } while (0)

  PSTAGE(0, 0);
  __syncthreads();
  for (int kt = 0; kt < HDIM / 32; ++kt) {
    const int cur = kt & 1;
    if (kt + 1 < HDIM / 32) PSTAGE(cur ^ 1, (kt + 1) * 32);
    u16x8 af[4], bfr[4];
    for (int m = 0; m < 4; ++m) {
      const int row = wm + m * 16 + cl;
      af[m] = *reinterpret_cast<const u16x8*>(
          &As[cur][row * 32 + ((rg ^ ((row >> 1) & 3)) * 8)]);
    }
    for (int n = 0; n < 4; ++n) {
      const int row = wn + n * 16 + cl;
      bfr[n] = *reinterpret_cast<const u16x8*>(
          &Bs[cur][row * 32 + ((rg ^ ((row >> 1) & 3)) * 8)]);
    }
    for (int m = 0; m < 4; ++m)
      for (int n = 0; n < 4; ++n)
        acc[m][n] = mfma16(af[m], bfr[n], acc[m][n]);
    __syncthreads();
  }
#undef PSTAGE

  const int z = n0g >> 10;
  const float* __restrict__ bias = (z == 0) ? bq : (z == 1) ? bk : bv;
  const int nbase = n0g & 1023;
  for (int n = 0; n < 4; ++n) {
    const int col = nbase + wn + n * 16 + cl;
    const float bval = bias[col];
    const int h = col >> 6, d = col & 63;
    for (int m = 0; m < 4; ++m) {
      const int rbase = m0 + wm + m * 16 + rg * 4;
      const int b = rbase >> 11, s = rbase & 2047;
      float v[4];
      for (int r = 0; r < 4; ++r) v[r] = acc[m][n][r] + bval;
      if (z == 0) {
        for (int r = 0; r < 4; ++r)
          Qs[((b * NH + h) * SEQ + s + r) * HD + d] =
              f2bf(v[r] * (0.125f * LOG2E));
      } else if (z == 1) {
        for (int r = 0; r < 4; ++r)
          Kb[((b * NH + h) * SEQ + s + r) * HD + d] = f2bf(v[r]);
      } else {
        u16x4 pk;
        for (int r = 0; r < 4; ++r) pk[r] = f2bf(v[r]);
        *reinterpret_cast<u16x4*>(&Vt[((b * NH + h) * HD + d) * SEQ + s]) = pk;
      }
    }
  }
}

// ---------- flash attention v4 (unchanged from round 7) ----------
#define SWZ(row) ((((row) & 3) << 1) | (((row) >> 3) & 1))
__global__ __launch_bounds__(256, 4) void attn_kernel(
    const unsigned short* __restrict__ Qs, const unsigned short* __restrict__ Kb,
    const unsigned short* __restrict__ Vt, const float* __restrict__ mask,
    float* __restrict__ out) {
  const int bid = blockIdx.x;
  const int lbid = (bid & 7) * 128 + (bid >> 3);
  const int head = lbid >> 4;
  const int qchunk = lbid & 15;
  const int b = head >> 4, h = head & 15;
  const int tid = threadIdx.x, lane = tid & 63, w = tid >> 6;
  const int q0 = qchunk * 128 + w * 32;
  const int cl = lane & 15, rg = lane >> 4;

  __shared__ unsigned short Kbuf[2][64 * 64];  // 16 KB [key][d], SWZ chunks
  __shared__ unsigned short Vbuf[2][64 * 64];  // 16 KB [d][key], SWZ chunks
  __shared__ float Mlds[SEQ];                  // 8 KB mask*LOG2E

  {
    const float* mrow = mask + b * SEQ;
    f32x4 m0 = *reinterpret_cast<const f32x4*>(mrow + tid * 8);
    f32x4 m1 = *reinterpret_cast<const f32x4*>(mrow + tid * 8 + 4);
    for (int j = 0; j < 4; ++j) {
      Mlds[tid * 8 + j] = m0[j] * LOG2E;
      Mlds[tid * 8 + 4 + j] = m1[j] * LOG2E;
    }
  }

  const int srow0 = tid >> 3, ch0 = tid & 7;
  const int srow1 = 32 + srow0;
  const unsigned short* kgA = Kb + (head * SEQ + srow0) * HD + ((ch0 ^ SWZ(srow0)) * 8);
  const unsigned short* kgB = Kb + (head * SEQ + srow1) * HD + ((ch0 ^ SWZ(srow1)) * 8);
  const unsigned short* vgA = Vt + (head * HD + srow0) * SEQ + ((ch0 ^ SWZ(srow0)) * 8);
  const unsigned short* vgB = Vt + (head * HD + srow1) * SEQ + ((ch0 ^ SWZ(srow1)) * 8);

#define STAGE(buf, kk)                                                         \
  do {                                                                         \
    GLOAD_LDS16(kgA + (size_t)(kk)*HD, &Kbuf[buf][tid * 8]);                   \
    GLOAD_LDS16(kgB + (size_t)(kk)*HD, &Kbuf[buf][(256 + tid) * 8]);           \
    GLOAD_LDS16(vgA + (kk), &Vbuf[buf][tid * 8]);                              \
    GLOAD_LDS16(vgB + (kk), &Vbuf[buf][(256 + tid) * 8]);                      \
  } while (0)

  u16x8 qf[2][2];
  for (int rf = 0; rf < 2; ++rf)
    for (int dc = 0; dc < 2; ++dc)
      qf[rf][dc] = *reinterpret_cast<const u16x8*>(
          Qs + (head * SEQ + q0 + rf * 16 + cl) * HD + dc * 32 + rg * 8);

  f32x4 ctx[2][4] = {};
  float lrow[2] = {0.f, 0.f};

  STAGE(0, 0);
  __syncthreads();

  for (int t = 0; t < SEQ / 64; ++t) {
    const int cur = t & 1;
    const int kk = t * 64;
    if (t + 1 < SEQ / 64) STAGE(cur ^ 1, kk + 64);

    for (int jj = 0; jj < 2; ++jj) {
      f32x4 mv0 = *reinterpret_cast<const f32x4*>(&Mlds[kk + jj * 32 + rg * 8]);
      f32x4 mv1 = *reinterpret_cast<const f32x4*>(&Mlds[kk + jj * 32 + rg * 8 + 4]);
      f32x4 sT[2][2];
      sT[0][0] = mv0; sT[0][1] = mv0;
      sT[1][0] = mv1; sT[1][1] = mv1;
      __builtin_amdgcn_s_setprio(1);
      for (int c = 0; c < 2; ++c) {
        const int krow = jj * 32 + ((cl >> 2) << 3) + (c << 2) + (cl & 3);
        u16x8 kf0 = *reinterpret_cast<const u16x8*>(
            &Kbuf[cur][krow * 64 + ((rg ^ SWZ(krow)) * 8)]);
        u16x8 kf1 = *reinterpret_cast<const u16x8*>(
            &Kbuf[cur][krow * 64 + (((4 | rg) ^ SWZ(krow)) * 8)]);
        for (int rf = 0; rf < 2; ++rf) {
          sT[c][rf] = mfma16(kf0, qf[rf][0], sT[c][rf]);
          sT[c][rf] = mfma16(kf1, qf[rf][1], sT[c][rf]);
        }
      }
      __builtin_amdgcn_s_setprio(0);
      bf16x8 pa[2];
      for (int rf = 0; rf < 2; ++rf)
        for (int c = 0; c < 2; ++c)
          for (int r = 0; r < 4; ++r) {
            float p = __builtin_amdgcn_exp2f(sT[c][rf][r]);
            lrow[rf] += p;
            pa[rf][c * 4 + r] = (__bf16)p;
          }
      __builtin_amdgcn_s_setprio(1);
      for (int df = 0; df < 4; ++df) {
        const int vrow = df * 16 + cl;
        u16x8 vf = *reinterpret_cast<const u16x8*>(
            &Vbuf[cur][vrow * 64 + (((jj * 4 + rg) ^ SWZ(vrow)) * 8)]);
        for (int rf = 0; rf < 2; ++rf)
          ctx[rf][df] = mfma16b(pa[rf], vf, ctx[rf][df]);
      }
      __builtin_amdgcn_s_setprio(0);
    }
    __syncthreads();
  }

  for (int rf = 0; rf < 2; ++rf) {
    lrow[rf] += __shfl_xor(lrow[rf], 16);
    lrow[rf] += __shfl_xor(lrow[rf], 32);
  }
  for (int rf = 0; rf < 2; ++rf) {
    float inv[4];
    for (int r = 0; r < 4; ++r)
      inv[r] = 1.0f / __shfl(lrow[rf], rg * 4 + r);
    for (int df = 0; df < 4; ++df)
      for (int r = 0; r < 4; ++r)
        out[(b * SEQ + q0 + rf * 16 + rg * 4 + r) * HDIM + h * HD + df * 16 + cl] =
            ctx[rf][df][r] * inv[r];
  }
#undef STAGE
}

extern "C" void kernel_launch(void* const* d_in, const int* in_sizes, int n_in,
                              void* d_out, int out_size, void* d_ws, size_t ws_size,
                              hipStream_t stream) {
  const float* hs   = (const float*)d_in[0];
  const float* mask = (const float*)d_in[1];
  // d_in[2] intent_ids, d_in[9..11] intent path: unused (softmax shift-invariant)
  const float* Wq = (const float*)d_in[3];
  const float* bq = (const float*)d_in[4];
  const float* Wk = (const float*)d_in[5];
  const float* bk = (const float*)d_in[6];
  const float* Wv = (const float*)d_in[7];
  const float* bv = (const float*)d_in[8];
  float* out = (float*)d_out;

  uint8_t* ws = (uint8_t*)d_ws;
  const size_t MB = 1024 * 1024;
  unsigned short* Xb   = (unsigned short*)(ws);            // 16 MB
  unsigned short* Wcat = (unsigned short*)(ws + 16 * MB);  // 6 MB: [3][1024][1024]
  unsigned short* Qsp  = (unsigned short*)(ws + 22 * MB);  // 16 MB: [64][2048][64]
  unsigned short* Kbp  = (unsigned short*)(ws + 38 * MB);  // 16 MB
  unsigned short* Vtp  = (unsigned short*)(ws + 54 * MB);  // 16 MB: [64][64][2048]

  cvt_x_kernel<<<4096, 256, 0, stream>>>(hs, Xb);
  cvt_wt_kernel<<<dim3(16, 16, 3), 256, 0, stream>>>(Wq, Wk, Wv, Wcat);
  proj_kernel<<<dim3(64, 24), 256, 0, stream>>>(Xb, Wcat, bq, bk, bv,
                                                Qsp, Kbp, Vtp);
  attn_kernel<<<1024, 256, 0, stream>>>(Qsp, Kbp, Vtp, mask, out);
}

// Round 9
// 157.266 us; speedup vs baseline: 1.4410x; 1.0226x over previous
//
#include <hip/hip_runtime.h>
#include <stdint.h>

#define NH    16
#define HD    64
#define HDIM  1024
#define BATCH 4
#define SEQ   2048

typedef __attribute__((ext_vector_type(4))) float f32x4;
typedef __attribute__((ext_vector_type(8))) __bf16 bf16x8;
typedef __attribute__((ext_vector_type(8))) unsigned short u16x8;
typedef __attribute__((ext_vector_type(4))) unsigned short u16x4;

#define LOG2E 1.44269504088896340736f

__device__ __forceinline__ unsigned short f2bf(float f) {
  unsigned int u = __builtin_bit_cast(unsigned int, f);
  u += 0x7fffu + ((u >> 16) & 1u);   // RNE
  return (unsigned short)(u >> 16);
}

__device__ __forceinline__ f32x4 mfma16(u16x8 a, u16x8 b, f32x4 c) {
  return __builtin_amdgcn_mfma_f32_16x16x32_bf16(
      __builtin_bit_cast(bf16x8, a), __builtin_bit_cast(bf16x8, b), c, 0, 0, 0);
}

__device__ __forceinline__ f32x4 mfma16b(bf16x8 a, u16x8 b, f32x4 c) {
  return __builtin_amdgcn_mfma_f32_16x16x32_bf16(
      a, __builtin_bit_cast(bf16x8, b), c, 0, 0, 0);
}

#define GLOAD_LDS16(g, l)                                                      \
  __builtin_amdgcn_global_load_lds(                                            \
      (const __attribute__((address_space(1))) unsigned int*)(g),              \
      (__attribute__((address_space(3))) unsigned int*)(l), 16, 0, 0)

// ---------- fp32 -> bf16 bits, x8 vectorized ----------
__global__ __launch_bounds__(256) void cvt_x_kernel(
    const float* __restrict__ src, unsigned short* __restrict__ dst) {
  int i = (blockIdx.x * 256 + threadIdx.x) * 8;
  f32x4 a = *reinterpret_cast<const f32x4*>(src + i);
  f32x4 b = *reinterpret_cast<const f32x4*>(src + i + 4);
  u16x8 o;
  o[0] = f2bf(a[0]); o[1] = f2bf(a[1]); o[2] = f2bf(a[2]); o[3] = f2bf(a[3]);
  o[4] = f2bf(b[0]); o[5] = f2bf(b[1]); o[6] = f2bf(b[2]); o[7] = f2bf(b[3]);
  *reinterpret_cast<u16x8*>(dst + i) = o;
}

// ---------- W[k][n] fp32 -> Wcat[z][n][k] bf16, LDS-tiled transpose ----------
__global__ __launch_bounds__(256) void cvt_wt_kernel(
    const float* __restrict__ Wq, const float* __restrict__ Wk,
    const float* __restrict__ Wv, unsigned short* __restrict__ Wcat) {
  const float* __restrict__ src =
      (blockIdx.z == 0) ? Wq : (blockIdx.z == 1) ? Wk : Wv;
  unsigned short* __restrict__ dst = Wcat + (size_t)blockIdx.z * HDIM * HDIM;
  __shared__ float T[64][65];
  const int k0 = blockIdx.y * 64, n0 = blockIdx.x * 64;
  const int tid = threadIdx.x;
  const int lrow = tid >> 4, c4 = (tid & 15) * 4;
  for (int it = 0; it < 4; ++it) {
    f32x4 v = *reinterpret_cast<const f32x4*>(
        &src[(k0 + it * 16 + lrow) * HDIM + n0 + c4]);
    T[it * 16 + lrow][c4 + 0] = v[0];
    T[it * 16 + lrow][c4 + 1] = v[1];
    T[it * 16 + lrow][c4 + 2] = v[2];
    T[it * 16 + lrow][c4 + 3] = v[3];
  }
  __syncthreads();
  const int n = tid >> 2, kc = (tid & 3) * 16;
  u16x8 o0, o1;
  for (int j = 0; j < 8; ++j) o0[j] = f2bf(T[kc + j][n]);
  for (int j = 0; j < 8; ++j) o1[j] = f2bf(T[kc + 8 + j][n]);
  *reinterpret_cast<u16x8*>(&dst[(n0 + n) * HDIM + k0 + kc]) = o0;
  *reinterpret_cast<u16x8*>(&dst[(n0 + n) * HDIM + k0 + kc + 8]) = o1;
}

// ---------- fused QKV projection: [8192x1024] @ [1024x3072] ----------
// 128x128 tile, BK=32 double-buffered 2-phase, conflict-free swizzle
// (measured 0 conflicts, round 8). Round-9 changes:
// (a) XCD-chunked bid swizzle: XCD x owns mi in [8x,8x+8) x all ni, ordered
//     ni-outer/mi-inner -> A-panel (2MB) L2-resident per XCD, B-tile reused
//     by 8 consecutive blocks. 1536 = 8*192 -> bijective.
// (b) Epilogue line-completion order: Q/K n-innermost (4 insts complete each
//     128B line), V m-innermost -- kills the 1.85x write amplification seen
//     in round 8 (partial 32B line pieces evicted under n-outer order).
__global__ __launch_bounds__(256, 4) void proj_kernel(
    const unsigned short* __restrict__ Xb,
    const unsigned short* __restrict__ Wcat,
    const float* __restrict__ bq, const float* __restrict__ bk,
    const float* __restrict__ bv,
    unsigned short* __restrict__ Qs, unsigned short* __restrict__ Kb,
    unsigned short* __restrict__ Vt) {
  const int bid = blockIdx.x;
  const int xcd = bid & 7, i = bid >> 3;
  const int mi = xcd * 8 + (i & 7);      // 0..63
  const int ni = i >> 3;                 // 0..23
  const int m0 = mi * 128;
  const int n0g = ni * 128;
  __shared__ unsigned short As[2][128 * 32];   // 8 KB each buf
  __shared__ unsigned short Bs[2][128 * 32];
  const int tid = threadIdx.x, lane = tid & 63, w = tid >> 6;
  const int wm = (w >> 1) * 64, wn = (w & 1) * 64;
  const int cl = lane & 15, rg = lane >> 4;
  f32x4 acc[4][4] = {};

#define PSTAGE(buf, k0)                                                        \
  do {                                                                         \
    for (int p = 0; p < 2; ++p) {                                              \
      int c = p * 256 + tid, row = c >> 2, ch = c & 3;                         \
      int sch = (ch ^ ((row >> 1) & 3)) * 8;                                   \
      GLOAD_LDS16(Xb + (m0 + row) * HDIM + (k0) + sch, &As[buf][c * 8]);       \
      GLOAD_LDS16(Wcat + (size_t)(n0g + row) * HDIM + (k0) + sch,              \
                  &Bs[buf][c * 8]);                                            \
    }                                                                          \
  } while (0)

  PSTAGE(0, 0);
  __syncthreads();
  for (int kt = 0; kt < HDIM / 32; ++kt) {
    const int cur = kt & 1;
    if (kt + 1 < HDIM / 32) PSTAGE(cur ^ 1, (kt + 1) * 32);
    u16x8 af[4], bfr[4];
    for (int m = 0; m < 4; ++m) {
      const int row = wm + m * 16 + cl;
      af[m] = *reinterpret_cast<const u16x8*>(
          &As[cur][row * 32 + ((rg ^ ((row >> 1) & 3)) * 8)]);
    }
    for (int n = 0; n < 4; ++n) {
      const int row = wn + n * 16 + cl;
      bfr[n] = *reinterpret_cast<const u16x8*>(
          &Bs[cur][row * 32 + ((rg ^ ((row >> 1) & 3)) * 8)]);
    }
    for (int m = 0; m < 4; ++m)
      for (int n = 0; n < 4; ++n)
        acc[m][n] = mfma16(af[m], bfr[n], acc[m][n]);
    __syncthreads();
  }
#undef PSTAGE

  const int z = n0g >> 10;
  const float* __restrict__ bias = (z == 0) ? bq : (z == 1) ? bk : bv;
  const int nbase = n0g & 1023;
  // hoisted per-n column parameters
  int hh[4], dd[4];
  float bvals[4];
  for (int n = 0; n < 4; ++n) {
    const int col = nbase + wn + n * 16 + cl;
    bvals[n] = bias[col];
    hh[n] = col >> 6;
    dd[n] = col & 63;
  }
  if (z == 2) {
    // V[b,h,d,s]: line = 64 consecutive s for fixed d -> m innermost
    for (int n = 0; n < 4; ++n) {
      for (int m = 0; m < 4; ++m) {
        const int rbase = m0 + wm + m * 16 + rg * 4;
        const int b = rbase >> 11, s = rbase & 2047;
        u16x4 pk;
        for (int r = 0; r < 4; ++r) pk[r] = f2bf(acc[m][n][r] + bvals[n]);
        *reinterpret_cast<u16x4*>(
            &Vt[(((size_t)b * NH + hh[n]) * HD + dd[n]) * SEQ + s]) = pk;
      }
    }
  } else {
    // Q/K[b,h,s,d]: line = 64 consecutive d for fixed s -> n innermost
    unsigned short* __restrict__ dst = (z == 0) ? Qs : Kb;
    const float sc = (z == 0) ? (0.125f * LOG2E) : 1.0f;   // *1.0f exact for K
    for (int m = 0; m < 4; ++m) {
      const int rbase = m0 + wm + m * 16 + rg * 4;
      const int b = rbase >> 11, s0 = rbase & 2047;
      for (int r = 0; r < 4; ++r) {
        const int srow = s0 + r;
        for (int n = 0; n < 4; ++n) {
          const float v = (acc[m][n][r] + bvals[n]) * sc;
          dst[(((size_t)b * NH + hh[n]) * SEQ + srow) * HD + dd[n]] = f2bf(v);
        }
      }
    }
  }
}

// ---------- flash attention v4 (unchanged from round 7) ----------
#define SWZ(row) ((((row) & 3) << 1) | (((row) >> 3) & 1))
__global__ __launch_bounds__(256, 4) void attn_kernel(
    const unsigned short* __restrict__ Qs, const unsigned short* __restrict__ Kb,
    const unsigned short* __restrict__ Vt, const float* __restrict__ mask,
    float* __restrict__ out) {
  const int bid = blockIdx.x;
  const int lbid = (bid & 7) * 128 + (bid >> 3);
  const int head = lbid >> 4;
  const int qchunk = lbid & 15;
  const int b = head >> 4, h = head & 15;
  const int tid = threadIdx.x, lane = tid & 63, w = tid >> 6;
  const int q0 = qchunk * 128 + w * 32;
  const int cl = lane & 15, rg = lane >> 4;

  __shared__ unsigned short Kbuf[2][64 * 64];  // 16 KB [key][d], SWZ chunks
  __shared__ unsigned short Vbuf[2][64 * 64];  // 16 KB [d][key], SWZ chunks
  __shared__ float Mlds[SEQ];                  // 8 KB mask*LOG2E

  {
    const float* mrow = mask + b * SEQ;
    f32x4 m0 = *reinterpret_cast<const f32x4*>(mrow + tid * 8);
    f32x4 m1 = *reinterpret_cast<const f32x4*>(mrow + tid * 8 + 4);
    for (int j = 0; j < 4; ++j) {
      Mlds[tid * 8 + j] = m0[j] * LOG2E;
      Mlds[tid * 8 + 4 + j] = m1[j] * LOG2E;
    }
  }

  const int srow0 = tid >> 3, ch0 = tid & 7;
  const int srow1 = 32 + srow0;
  const unsigned short* kgA = Kb + (head * SEQ + srow0) * HD + ((ch0 ^ SWZ(srow0)) * 8);
  const unsigned short* kgB = Kb + (head * SEQ + srow1) * HD + ((ch0 ^ SWZ(srow1)) * 8);
  const unsigned short* vgA = Vt + (head * HD + srow0) * SEQ + ((ch0 ^ SWZ(srow0)) * 8);
  const unsigned short* vgB = Vt + (head * HD + srow1) * SEQ + ((ch0 ^ SWZ(srow1)) * 8);

#define STAGE(buf, kk)                                                         \
  do {                                                                         \
    GLOAD_LDS16(kgA + (size_t)(kk)*HD, &Kbuf[buf][tid * 8]);                   \
    GLOAD_LDS16(kgB + (size_t)(kk)*HD, &Kbuf[buf][(256 + tid) * 8]);           \
    GLOAD_LDS16(vgA + (kk), &Vbuf[buf][tid * 8]);                              \
    GLOAD_LDS16(vgB + (kk), &Vbuf[buf][(256 + tid) * 8]);                      \
  } while (0)

  u16x8 qf[2][2];
  for (int rf = 0; rf < 2; ++rf)
    for (int dc = 0; dc < 2; ++dc)
      qf[rf][dc] = *reinterpret_cast<const u16x8*>(
          Qs + (head * SEQ + q0 + rf * 16 + cl) * HD + dc * 32 + rg * 8);

  f32x4 ctx[2][4] = {};
  float lrow[2] = {0.f, 0.f};

  STAGE(0, 0);
  __syncthreads();

  for (int t = 0; t < SEQ / 64; ++t) {
    const int cur = t & 1;
    const int kk = t * 64;
    if (t + 1 < SEQ / 64) STAGE(cur ^ 1, kk + 64);

    for (int jj = 0; jj < 2; ++jj) {
      f32x4 mv0 = *reinterpret_cast<const f32x4*>(&Mlds[kk + jj * 32 + rg * 8]);
      f32x4 mv1 = *reinterpret_cast<const f32x4*>(&Mlds[kk + jj * 32 + rg * 8 + 4]);
      f32x4 sT[2][2];
      sT[0][0] = mv0; sT[0][1] = mv0;
      sT[1][0] = mv1; sT[1][1] = mv1;
      __builtin_amdgcn_s_setprio(1);
      for (int c = 0; c < 2; ++c) {
        const int krow = jj * 32 + ((cl >> 2) << 3) + (c << 2) + (cl & 3);
        u16x8 kf0 = *reinterpret_cast<const u16x8*>(
            &Kbuf[cur][krow * 64 + ((rg ^ SWZ(krow)) * 8)]);
        u16x8 kf1 = *reinterpret_cast<const u16x8*>(
            &Kbuf[cur][krow * 64 + (((4 | rg) ^ SWZ(krow)) * 8)]);
        for (int rf = 0; rf < 2; ++rf) {
          sT[c][rf] = mfma16(kf0, qf[rf][0], sT[c][rf]);
          sT[c][rf] = mfma16(kf1, qf[rf][1], sT[c][rf]);
        }
      }
      __builtin_amdgcn_s_setprio(0);
      bf16x8 pa[2];
      for (int rf = 0; rf < 2; ++rf)
        for (int c = 0; c < 2; ++c)
          for (int r = 0; r < 4; ++r) {
            float p = __builtin_amdgcn_exp2f(sT[c][rf][r]);
            lrow[rf] += p;
            pa[rf][c * 4 + r] = (__bf16)p;
          }
      __builtin_amdgcn_s_setprio(1);
      for (int df = 0; df < 4; ++df) {
        const int vrow = df * 16 + cl;
        u16x8 vf = *reinterpret_cast<const u16x8*>(
            &Vbuf[cur][vrow * 64 + (((jj * 4 + rg) ^ SWZ(vrow)) * 8)]);
        for (int rf = 0; rf < 2; ++rf)
          ctx[rf][df] = mfma16b(pa[rf], vf, ctx[rf][df]);
      }
      __builtin_amdgcn_s_setprio(0);
    }
    __syncthreads();
  }

  for (int rf = 0; rf < 2; ++rf) {
    lrow[rf] += __shfl_xor(lrow[rf], 16);
    lrow[rf] += __shfl_xor(lrow[rf], 32);
  }
  for (int rf = 0; rf < 2; ++rf) {
    float inv[4];
    for (int r = 0; r < 4; ++r)
      inv[r] = 1.0f / __shfl(lrow[rf], rg * 4 + r);
    for (int df = 0; df < 4; ++df)
      for (int r = 0; r < 4; ++r)
        out[(b * SEQ + q0 + rf * 16 + rg * 4 + r) * HDIM + h * HD + df * 16 + cl] =
            ctx[rf][df][r] * inv[r];
  }
#undef STAGE
}

extern "C" void kernel_launch(void* const* d_in, const int* in_sizes, int n_in,
                              void* d_out, int out_size, void* d_ws, size_t ws_size,
                              hipStream_t stream) {
  const float* hs   = (const float*)d_in[0];
  const float* mask = (const float*)d_in[1];
  // d_in[2] intent_ids, d_in[9..11] intent path: unused (softmax shift-invariant)
  const float* Wq = (const float*)d_in[3];
  const float* bq = (const float*)d_in[4];
  const float* Wk = (const float*)d_in[5];
  const float* bk = (const float*)d_in[6];
  const float* Wv = (const float*)d_in[7];
  const float* bv = (const float*)d_in[8];
  float* out = (float*)d_out;

  uint8_t* ws = (uint8_t*)d_ws;
  const size_t MB = 1024 * 1024;
  unsigned short* Xb   = (unsigned short*)(ws);            // 16 MB
  unsigned short* Wcat = (unsigned short*)(ws + 16 * MB);  // 6 MB: [3][1024][1024]
  unsigned short* Qsp  = (unsigned short*)(ws + 22 * MB);  // 16 MB: [64][2048][64]
  unsigned short* Kbp  = (unsigned short*)(ws + 38 * MB);  // 16 MB
  unsigned short* Vtp  = (unsigned short*)(ws + 54 * MB);  // 16 MB: [64][64][2048]

  cvt_x_kernel<<<4096, 256, 0, stream>>>(hs, Xb);
  cvt_wt_kernel<<<dim3(16, 16, 3), 256, 0, stream>>>(Wq, Wk, Wv, Wcat);
  proj_kernel<<<1536, 256, 0, stream>>>(Xb, Wcat, bq, bk, bv, Qsp, Kbp, Vtp);
  attn_kernel<<<1024, 256, 0, stream>>>(Qsp, Kbp, Vtp, mask, out);
}